// Round 11
// baseline (63.349 us; speedup 1.0000x reference)
//
#include <hip/hip_runtime.h>
#include <hip/hip_bf16.h>

#define NS     32768
#define NROWS  2048
#define HOP    127
#define NW     257
#define NB     128
#define WTILE  16
#define NT     17            // sub-tiles of 16 windows; sub-tile 16 has 1 valid window
#define TWOPI_255 0.02463994236f   // 2*pi/255

typedef _Float16 f16;
typedef __attribute__((ext_vector_type(2))) _Float16 f16x2;
typedef __attribute__((ext_vector_type(4))) _Float16 f16x4;
typedef __attribute__((ext_vector_type(8))) _Float16 f16x8;
typedef __attribute__((ext_vector_type(4))) float f32x4;

__device__ inline f32x4 load4u(const char* p) {  // 4B-aligned 16B load
    f32x4 v;
    __builtin_memcpy(&v, p, 16);
    return v;
}

// ---------------------------------------------------------------------------
// Kernel 1: folded-DFT basis table (64 KB) in fragment order (as round 8).
// Fragment fi: comp = (fi>>5)*128 + ((fi>>3)&3)*32 + ((fi>>2)&1)*16 + (l&15),
// k = (fi&3)*32 + (l>>4)*8 + j.
// ---------------------------------------------------------------------------
__global__ __launch_bounds__(256)
void basis_kernel(f16* __restrict__ bt) {
    const int t  = blockIdx.x * 256 + threadIdx.x;   // 0..4095
    const int fi = t >> 6;
    const int l  = t & 63;
    const int cq = fi >> 3;
    const int nt = (fi >> 2) & 1;
    const int kk = fi & 3;
    const int is_sin = cq >> 2;
    const int f  = (cq & 3) * 32 + nt * 16 + (l & 15);   // freq 0..127
    int m = (f * (kk * 32 + (l >> 4) * 8)) % 255;
    f16x8 v;
    #pragma unroll
    for (int j = 0; j < 8; ++j) {
        const float ang = (float)m * TWOPI_255;
        v[j] = (f16)(is_sin ? __sinf(ang) : __cosf(ang));
        m += f; if (m >= 255) m -= 255;
    }
    *(f16x8*)(bt + (size_t)t * 8) = v;   // 16B/thread, coalesced
}

// ---------------------------------------------------------------------------
// Kernel 2: one block (8 waves, 512 thr) per row. Wave cq = (mg,hs,ng):
//   mg = cq>>2   : processes sub-tiles with (st&1)==mg  -> LDS reads halved
//   hs = (cq>>1)&1 : 0=cos(y+), 1=sin(y-)
//   ng = cq&1    : comp group of 64 -> bfrag[4][4] = 64 VGPR
// __launch_bounds__(512,4) caps VGPR at 128 (round-9 lesson: >128 at 512thr
// means 1 block/CU). Quad-buffered 16-window sub-tiles, barrier every other
// sub-tile (hazards span >=1 barrier; parity shifts reads by 0 or +-2 which
// preserves the distance-4 reuse argument).
// K folded 255->128: y+[k]=x[k]+x[255-k] (cos), y-[k]=x[k]-x[255-k] (sin).
// S[f] = (sum_w Ccos^2 + Csin^2)/257.
// ---------------------------------------------------------------------------
__global__ __launch_bounds__(512, 4)
void psd_kernel(const float* __restrict__ X, const f16* __restrict__ bt,
                float* __restrict__ out) {
    const int row  = blockIdx.x;
    const int tid  = threadIdx.x;
    const int lane = tid & 63;
    const int cq   = tid >> 6;      // wave 0..7
    const int r16  = lane & 15;
    const int kg   = lane >> 4;
    const int mg   = cq >> 2;       // sub-tile parity owner
    const int hs   = (cq >> 1) & 1; // cos/sin half
    const int ng   = cq & 1;        // comp-64 group

    __shared__ alignas(16) f16 atile[4][WTILE * 256];  // 4 x 8 KB, XOR-swizzled
    __shared__ float scol[2][256];

    const char* __restrict__ xrow = (const char*)(X + (size_t)row * NS);

    const int sw  = tid >> 5;           // staging window 0..15
    const int sq  = tid & 31;           // staging k-quad 0..31

    // loop-invariant per-lane global byte offsets (tile-local)
    const uint voff_f = (uint)((sw * HOP + sq * 4) * 4);
    const uint voff_r = (uint)((sw * HOP + 252 - sq * 4) * 4);
    const uint vclamp = (uint)((NS - 4) * 4);

    // ---- sub-tile-0 staging loads ----
    f32x4 fv = load4u(xrow + voff_f);
    f32x4 rv = load4u(xrow + voff_r);

    // ---- basis fragments: 64 comps/wave = 16 coalesced dwordx4 (L2-resident) ----
    f16x8 bfrag[4][4];
    {
        const char* bp = (const char*)bt + (uint)(lane * 16);
        #pragma unroll
        for (int m = 0; m < 4; ++m) {
            const int fi0 = hs * 32 + (ng * 2 + (m >> 1)) * 8 + (m & 1) * 4;
            #pragma unroll
            for (int kk = 0; kk < 4; ++kk)
                bfrag[m][kk] = *(const f16x8*)(bp + (uint)((fi0 + kk) * 1024));
        }
    }

    char* const lds = (char*)&atile[0][0];

    // hoisted LDS byte offsets
    const uint swz  = (uint)((sw & 7) << 4);
    const uint wr_p = ((uint)(sw * 512 + sq * 8)) ^ swz;         // y+ (8B)
    const uint wr_m = ((uint)(sw * 512 + sq * 8 + 256)) ^ swz;   // y- (8B)
    const uint rswz = (uint)((r16 & 7) << 4);
    uint rd[4];
    #pragma unroll
    for (int kk = 0; kk < 4; ++kk)
        rd[kk] = ((uint)(r16 * 512 + hs * 256 + kg * 16 + kk * 64)) ^ rswz;

    // ---- packed fold (4 pairs) + 2 x ds_write_b64 ----
    auto fold_write = [&](char* wp, bool valid) {
        // partner of k=sq*4+j is rv[3-j]
        const f16x2 fp01 = __builtin_bit_cast(f16x2, __builtin_amdgcn_cvt_pkrtz(fv[0], fv[1]));
        const f16x2 fp23 = __builtin_bit_cast(f16x2, __builtin_amdgcn_cvt_pkrtz(fv[2], fv[3]));
        const f16x2 rp01 = __builtin_bit_cast(f16x2, __builtin_amdgcn_cvt_pkrtz(rv[3], rv[2]));
        const f16x2 rp23 = __builtin_bit_cast(f16x2, __builtin_amdgcn_cvt_pkrtz(rv[1], rv[0]));
        const f16x2 yp01 = fp01 + rp01, yp23 = fp23 + rp23;
        const f16x2 ym01 = fp01 - rp01, ym23 = fp23 - rp23;
        f16x4 h0, h1;
        h0[0] = yp01[0]; h0[1] = yp01[1]; h0[2] = yp23[0]; h0[3] = yp23[1];
        h1[0] = ym01[0]; h1[1] = ym01[1]; h1[2] = ym23[0]; h1[3] = ym23[1];
        if (sq == 0) { h0[0] = (f16)fv[0]; h1[0] = (f16)0.0f; }  // k=0: pad partner
        if (!valid) {
            #pragma unroll
            for (int j = 0; j < 4; ++j) { h0[j] = (f16)0.0f; h1[j] = (f16)0.0f; }
        }
        *(f16x4*)(wp + wr_p) = h0;
        *(f16x4*)(wp + wr_m) = h1;
    };

    // ---- prologue: fold st0, st1; issue st2 loads; one barrier ----
    fold_write(lds + (0 << 13), true);
    {
        const uint tb = (uint)(1 * WTILE * HOP * 4);
        fv = load4u(xrow + (voff_f + tb));
        rv = load4u(xrow + (voff_r + tb));
    }
    fold_write(lds + (1 << 13), true);
    {
        const uint tb = (uint)(2 * WTILE * HOP * 4);
        fv = load4u(xrow + (voff_f + tb));
        rv = load4u(xrow + (voff_r + tb));
    }
    asm volatile("s_waitcnt lgkmcnt(0)" ::: "memory");
    __builtin_amdgcn_s_barrier();
    asm volatile("" ::: "memory");

    float ssum[4] = {0.f, 0.f, 0.f, 0.f};

    // iter mt: wave with mg==(mt&1) MFMAs buf[mt&3]; all fold st=mt+2;
    // issue loads st=mt+3; barrier after odd iters only.
    for (int mt = 0; mt < NT; ++mt) {
        if ((mt & 1) == mg) {
            const char* ap = lds + ((mt & 3) << 13);
            f32x4 acc0 = {0,0,0,0}, acc1 = {0,0,0,0}, acc2 = {0,0,0,0}, acc3 = {0,0,0,0};
            __builtin_amdgcn_s_setprio(1);
            #pragma unroll
            for (int kk = 0; kk < 4; ++kk) {
                const f16x8 af = *(const f16x8*)(ap + rd[kk]);
                acc0 = __builtin_amdgcn_mfma_f32_16x16x32_f16(af, bfrag[0][kk], acc0, 0, 0, 0);
                acc1 = __builtin_amdgcn_mfma_f32_16x16x32_f16(af, bfrag[1][kk], acc1, 0, 0, 0);
                acc2 = __builtin_amdgcn_mfma_f32_16x16x32_f16(af, bfrag[2][kk], acc2, 0, 0, 0);
                acc3 = __builtin_amdgcn_mfma_f32_16x16x32_f16(af, bfrag[3][kk], acc3, 0, 0, 0);
            }
            __builtin_amdgcn_s_setprio(0);
            #pragma unroll
            for (int r = 0; r < 4; ++r) {
                ssum[0] += acc0[r] * acc0[r];
                ssum[1] += acc1[r] * acc1[r];
                ssum[2] += acc2[r] * acc2[r];
                ssum[3] += acc3[r] * acc3[r];
            }
        }

        if (mt + 2 < NT) {
            // fold+write sub-tile mt+2 (loads issued one iteration ago)
            char* wp = lds + (((mt + 2) & 3) << 13);
            const bool valid = (mt + 2 != 16) || (sw == 0);  // st16: only window 256
            fold_write(wp, valid);
            if (mt + 3 < NT) {   // issue loads for st=mt+3; in flight across barrier
                const uint tb = (uint)((mt + 3) * WTILE * HOP * 4);
                fv = load4u(xrow + min(voff_f + tb, vclamp));
                rv = load4u(xrow + min(voff_r + tb, vclamp));
            }
        }
        if (mt & 1) {
            asm volatile("s_waitcnt lgkmcnt(0)" ::: "memory");  // drain ds ops only
            __builtin_amdgcn_s_barrier();
            asm volatile("" ::: "memory");
        }
    }

    // ---- reduce over k-groups (D col = lane&15); scol[mg][comp] ----
    #pragma unroll
    for (int m = 0; m < 4; ++m) {
        float v = ssum[m];
        v += __shfl_xor(v, 16, 64);
        v += __shfl_xor(v, 32, 64);
        if (kg == 0) scol[mg][hs * 128 + ng * 64 + m * 16 + r16] = v;
    }
    __syncthreads();
    if (tid < NB) {
        const float s = scol[0][tid] + scol[0][tid + NB]
                      + scol[1][tid] + scol[1][tid + NB];
        out[(size_t)row * NB + tid] = s * (1.0f / 257.0f);
    }
}

extern "C" void kernel_launch(void* const* d_in, const int* in_sizes, int n_in,
                              void* d_out, int out_size, void* d_ws, size_t ws_size,
                              hipStream_t stream) {
    const float* X = (const float*)d_in[0];
    float* out = (float*)d_out;
    f16* bt = (f16*)d_ws;   // 64 KB basis table
    (void)in_sizes; (void)n_in; (void)ws_size; (void)out_size;
    basis_kernel<<<dim3(16), dim3(256), 0, stream>>>(bt);
    psd_kernel<<<dim3(NROWS), dim3(512), 0, stream>>>(X, bt, out);
}